// Round 17
// baseline (571.790 us; speedup 1.0000x reference)
//
#include <hip/hip_runtime.h>
#include <hip/hip_bf16.h>

typedef unsigned int uint;
typedef unsigned short ushort;

#define NN 65536
#define NE 1048576
#define DD 128
#define TOTE (NE + NN)   // 1114112

__device__ __forceinline__ float b2f(ushort u) {
    uint v = ((uint)u) << 16; float f; __builtin_memcpy(&f, &v, 4); return f;
}
__device__ __forceinline__ ushort f2b(float f) {
    uint x; __builtin_memcpy(&x, &f, 4);
    uint r = (x + 0x7fffu + ((x >> 16) & 1u)) >> 16;
    return (ushort)r;
}

typedef __bf16 bf16x8 __attribute__((ext_vector_type(8)));
typedef float f32x4 __attribute__((ext_vector_type(4)));
typedef float f32x2 __attribute__((ext_vector_type(2)));

// unpack 2 bf16 (packed in uint) -> packed float2, no cvt needed
__device__ __forceinline__ f32x2 bf2f2(uint u) {
    union { uint i; float f; } lo, hi;
    lo.i = u << 16; hi.i = u & 0xffff0000u;
    return (f32x2){lo.f, hi.f};
}

// Canary protocol (kept permanently; perf-free): each pre-final kernel writes a
// distinct constant into a distinct slot of out[0..9]; the FINAL k_attn
// overwrites them with real values. On a mid-pipeline failure, absmax decodes
// the last kernel that ran (100,120,...,280; bands disjoint vs max|ref|=6.5).

// ---------- init: transpose W (fp32 k-major -> bf16 n-major) + zero cnt/sumbuf ----------
__global__ void k_init(const float* __restrict__ Wl, const float* __restrict__ Wr,
                       ushort* __restrict__ WT, int* __restrict__ cnt, float* __restrict__ sumbuf,
                       float* __restrict__ cano) {
    if (cano && blockIdx.x == 0 && blockIdx.y == 0 && blockIdx.z == 0 && threadIdx.x == 0)
        cano[0] = 100.0f;
    // grid (128, 2, 3), block 128
    int k = blockIdx.x, n = threadIdx.x, lr = blockIdx.y, layer = blockIdx.z;
    const float* W = (lr ? Wr : Wl) + layer * 16384;
    WT[(layer * 2 + lr) * 16384 + n * 128 + k] = f2b(W[k * 128 + n]);
    int gid = ((blockIdx.z * 2 + blockIdx.y) * 128 + blockIdx.x) * 128 + threadIdx.x;
    if (gid < NN) cnt[gid] = 0;
    if (gid == NN) sumbuf[0] = 0.f;
}

// ---------- histogram by dst (+self loops) fused with edge_attr sum — 4 edges/thread ----------
__global__ void k_histsum(const int* __restrict__ dst, const float* __restrict__ ea,
                          int* __restrict__ cnt, float* __restrict__ sum,
                          float* __restrict__ cano) {
    if (cano && blockIdx.x == 0 && threadIdx.x == 0) cano[1] = 120.0f;
    __shared__ float red[256];
    int t = threadIdx.x;
    int e0 = (blockIdx.x * 256 + t) * 4;
    float s = 0.f;
    if (e0 < NE) {
        int4  d4 = *(const int4*)&dst[e0];
        float4 a4 = *(const float4*)&ea[e0];
        atomicAdd(&cnt[d4.x], 1); atomicAdd(&cnt[d4.y], 1);
        atomicAdd(&cnt[d4.z], 1); atomicAdd(&cnt[d4.w], 1);
        s = (a4.x + a4.y) + (a4.z + a4.w);
    } else {
        int b = e0 - NE;
        atomicAdd(&cnt[b], 1);     atomicAdd(&cnt[b + 1], 1);
        atomicAdd(&cnt[b + 2], 1); atomicAdd(&cnt[b + 3], 1);
    }
    red[t] = s; __syncthreads();
    for (int o = 128; o > 0; o >>= 1) { if (t < o) red[t] += red[t + o]; __syncthreads(); }
    if (t == 0 && red[0] != 0.f) atomicAdd(sum, red[0]);
}

__global__ void k_scanA(const int* __restrict__ cnt, int* __restrict__ row_off, int* __restrict__ bsum,
                        float* __restrict__ cano) {
    if (cano && blockIdx.x == 0 && threadIdx.x == 0) cano[2] = 140.0f;
    __shared__ int tmp[256];
    int t = threadIdx.x, i = blockIdx.x * 256 + t;
    int v = cnt[i]; tmp[t] = v; __syncthreads();
    for (int off = 1; off < 256; off <<= 1) {
        int x = (t >= off) ? tmp[t - off] : 0;
        __syncthreads();
        tmp[t] += x;
        __syncthreads();
    }
    row_off[i] = tmp[t] - v;
    if (t == 255) bsum[blockIdx.x] = tmp[255];
}

// scanC with local re-scan of bsum (eliminates scanB dispatch)
__global__ void k_scanC(int* __restrict__ row_off, const int* __restrict__ bsum, int* __restrict__ cursor,
                        float* __restrict__ cano) {
    if (cano && blockIdx.x == 0 && threadIdx.x == 0) cano[3] = 160.0f;
    __shared__ int tmp[256];
    __shared__ int excl[256];
    int t = threadIdx.x;
    int v = bsum[t]; tmp[t] = v; __syncthreads();
    for (int off = 1; off < 256; off <<= 1) {
        int x = (t >= off) ? tmp[t - off] : 0;
        __syncthreads();
        tmp[t] += x;
        __syncthreads();
    }
    excl[t] = tmp[t] - v;
    __syncthreads();
    int offb = excl[blockIdx.x];
    int i = blockIdx.x * 256 + t;
    int nv = row_off[i] + offb;
    row_off[i] = nv;
    cursor[i] = nv;
    if (i == 0) row_off[NN] = TOTE;
}

// adj.x stores src<<8 (byte offset into bf16 row array: src*128ch*2B) — 4 edges/thread
__global__ void k_scatter(const int* __restrict__ src, const int* __restrict__ dst,
                          const float* __restrict__ ea, const float* __restrict__ sum,
                          int* __restrict__ cursor, int2* __restrict__ adj,
                          float* __restrict__ cano) {
    if (cano && blockIdx.x == 0 && threadIdx.x == 0) cano[4] = 180.0f;
    int e0 = (blockIdx.x * 256 + threadIdx.x) * 4;
    if (e0 < NE) {
        int4  s4 = *(const int4*)&src[e0];
        int4  d4 = *(const int4*)&dst[e0];
        float4 a4 = *(const float4*)&ea[e0];
        int p0 = atomicAdd(&cursor[d4.x], 1); adj[p0] = make_int2(s4.x << 8, __float_as_int(a4.x));
        int p1 = atomicAdd(&cursor[d4.y], 1); adj[p1] = make_int2(s4.y << 8, __float_as_int(a4.y));
        int p2 = atomicAdd(&cursor[d4.z], 1); adj[p2] = make_int2(s4.z << 8, __float_as_int(a4.z));
        int p3 = atomicAdd(&cursor[d4.w], 1); adj[p3] = make_int2(s4.w << 8, __float_as_int(a4.w));
    } else {
        int b = e0 - NE;
        float a = sum[0] * (1.0f / NE);
        #pragma unroll
        for (int k = 0; k < 4; k++) {
            int p = atomicAdd(&cursor[b + k], 1);
            adj[p] = make_int2((b + k) << 8, __float_as_int(a));
        }
    }
}

// ---------- dual GEMM (R14/R15-verified): B-in-LDS, A hoisted to regs, LDS-transposed epilogue ----------
template<bool F32SRC>
__global__ __launch_bounds__(512) void k_gemm(const void* __restrict__ srcv, const ushort* __restrict__ WT,
                                              const float* __restrict__ bl, const float* __restrict__ br,
                                              ushort* __restrict__ xl, ushort* __restrict__ xr,
                                              float* __restrict__ cano, int cslot, float cval) {
    if (cano && blockIdx.x == 0 && threadIdx.x == 0) cano[cslot] = cval;
    __shared__ __align__(16) ushort S[32768];   // 64KB: B [2][16][128][8], then C [2][128][128]

    int t = threadIdx.x;
    int rowbase = blockIdx.x * 128;

    #pragma unroll
    for (int i = 0; i < 8; i++) {
        int idx = i * 512 + t;            // 0..4095 chunks of 8 bf16
        int m = idx >> 11, n = (idx >> 4) & 127, c = idx & 15;
        *(bf16x8*)&S[m * 16384 + c * 1024 + n * 8] =
            *(const bf16x8*)&WT[m * 16384 + n * 128 + c * 8];
    }

    int wave = t >> 6, lane = t & 63;
    int row16 = lane & 15, quad = lane >> 4;
    int myrow = rowbase + wave * 16 + row16;

    // A fragments: issue ALL loads before the barrier (overlap B staging)
    bf16x8 areg[4];
    if (F32SRC) {
        const float* src = (const float*)srcv;
        float4 av[8];
        #pragma unroll
        for (int ks = 0; ks < 4; ks++) {
            const float* pa = &src[(size_t)myrow * 128 + ks * 32 + quad * 8];
            av[2 * ks]     = *(const float4*)pa;
            av[2 * ks + 1] = *(const float4*)(pa + 4);
        }
        #pragma unroll
        for (int ks = 0; ks < 4; ks++) {
            ushort u[8] = {f2b(av[2 * ks].x), f2b(av[2 * ks].y), f2b(av[2 * ks].z), f2b(av[2 * ks].w),
                           f2b(av[2 * ks + 1].x), f2b(av[2 * ks + 1].y), f2b(av[2 * ks + 1].z), f2b(av[2 * ks + 1].w)};
            __builtin_memcpy(&areg[ks], u, 16);
        }
    } else {
        const ushort* src = (const ushort*)srcv;
        #pragma unroll
        for (int ks = 0; ks < 4; ks++)
            areg[ks] = *(const bf16x8*)&src[(size_t)myrow * 128 + ks * 32 + quad * 8];
    }

    float bbl[8], bbr[8];
    #pragma unroll
    for (int tc = 0; tc < 8; tc++) { bbl[tc] = bl[tc * 16 + row16]; bbr[tc] = br[tc * 16 + row16]; }

    f32x4 accl[8], accr[8];
    #pragma unroll
    for (int i = 0; i < 8; i++) {
        accl[i] = (f32x4){0.f, 0.f, 0.f, 0.f};
        accr[i] = (f32x4){0.f, 0.f, 0.f, 0.f};
    }

    __syncthreads();   // B staged (A already in registers)

    #pragma unroll
    for (int ks = 0; ks < 4; ks++) {
        int chunk = ks * 4 + quad;
        #pragma unroll
        for (int tc = 0; tc < 8; tc++) {
            int coln = tc * 16 + row16;
            bf16x8 b_l = *(const bf16x8*)&S[chunk * 1024 + coln * 8];
            bf16x8 b_r = *(const bf16x8*)&S[16384 + chunk * 1024 + coln * 8];
            accl[tc] = __builtin_amdgcn_mfma_f32_16x16x32_bf16(areg[ks], b_l, accl[tc], 0, 0, 0);
            accr[tc] = __builtin_amdgcn_mfma_f32_16x16x32_bf16(areg[ks], b_r, accr[tc], 0, 0, 0);
        }
    }

    __syncthreads();   // all B reads done; S reusable for C

    #pragma unroll
    for (int tc = 0; tc < 8; tc++) {
        int col = tc * 16 + row16;
        #pragma unroll
        for (int r = 0; r < 4; r++) {
            int row = wave * 16 + quad * 4 + r;        // C/D: row = quad*4 + reg
            S[row * 128 + col]         = f2b(accl[tc][r] + bbl[tc]);
            S[16384 + row * 128 + col] = f2b(accr[tc][r] + bbr[tc]);
        }
    }
    __syncthreads();

    #pragma unroll
    for (int i = 0; i < 8; i++) {
        int idx = i * 512 + t;
        int m = idx >> 11, row = (idx >> 4) & 127, c8 = idx & 15;
        bf16x8 v = *(const bf16x8*)&S[m * 16384 + row * 128 + c8 * 8];
        ushort* dst = m ? xr : xl;
        *(bf16x8*)&dst[(size_t)(rowbase + row) * 128 + c8 * 8] = v;
    }
}

// ---------- fused attention: 2 nodes/wave, DUAL interleaved prologue (feed-rate attack) ----------
// R8-R11/R15 DATA: attn time == blocks / (constant ~46K threads/us feed rate)
// (R8: 32768/372 blocks-per-us = 88us; R11: 16384 double blocks/176 = 93us) —
// occupancy pinned ~40% because resident = rate x lifetime, both fixed. Escape:
// HALVE TOTAL THREADS. Each wave handles 2 consecutive nodes with BOTH nodes'
// 4-group prologues issued back-to-back (24 loads in flight) before consuming —
// parallel, not serial (R10's 8-SERIAL-node failure mode avoided).
// __launch_bounds__(128,2): 256-VGPR ceiling, no spill at ~130 live regs
// (R9 lesson: min-waves=8's 64-cap spilled; occupancy is feed-limited anyway).
template<int H, bool FINAL>
__global__ __launch_bounds__(128, 2) void k_attn(
    const ushort* __restrict__ xl, const ushort* __restrict__ xr,
    const int* __restrict__ row_off, const int2* __restrict__ adj,
    const float* __restrict__ We, const float* __restrict__ att,
    const float* __restrict__ bias, const float* __restrict__ ln_g, const float* __restrict__ ln_b,
    const float* __restrict__ hin, float* __restrict__ hout, ushort* __restrict__ hb,
    float* __restrict__ outp,
    float* __restrict__ cano, int cslot, float cval)
{
    if (cano && blockIdx.x == 0 && threadIdx.x == 0) cano[cslot] = cval;
    __shared__ float accbuf[2][8][160];   // [wave][p][cl*20 + 0..15] — bank-spread layout

    int wv = threadIdx.x >> 6, lane = threadIdx.x & 63;
    int p = lane >> 3;          // edge slot within 8-edge group
    int cl = lane & 7;          // channel block: ch [16*cl, 16*cl+16)
    int c16 = cl * 16;
    const char* xlb = (const char*)xl;

    // shared register caches
    f32x2 we2[8], at2[8];
    #pragma unroll
    for (int k = 0; k < 8; k++) {
        we2[k] = (f32x2){We[c16 + 2 * k], We[c16 + 2 * k + 1]};
        at2[k] = (f32x2){att[c16 + 2 * k], att[c16 + 2 * k + 1]};
    }
    int c0 = 2 * lane;
    int rb = (c0 >> 4) * 20 + (c0 & 15);

    int nA = blockIdx.x * 4 + wv * 2;    // this wave's two nodes: nA, nA+1
    int nB = nA + 1;
    int s0a = row_off[nA];
    int s1a = row_off[nA + 1];
    int s1b = row_off[nA + 2];
    int s0b = s1a;

    // xr rows for both nodes (staged raw)
    uint4 xra0 = *(const uint4*)&xr[(size_t)nA * 128 + c16];
    uint4 xra1 = *(const uint4*)&xr[(size_t)nA * 128 + c16 + 8];
    uint4 xrb0 = *(const uint4*)&xr[(size_t)nB * 128 + c16];
    uint4 xrb1 = *(const uint4*)&xr[(size_t)nB * 128 + c16 + 8];

    // ---- adj prologue for BOTH nodes ----
    int jA0 = s0a + p, jA1 = s0a + 8 + p, jA2 = s0a + 16 + p, jA3 = s0a + 24 + p;
    int2 aA0 = adj[(jA0 < s1a) ? jA0 : s0a];
    int2 aA1 = adj[(jA1 < s1a) ? jA1 : s0a];
    int2 aA2 = adj[(jA2 < s1a) ? jA2 : s0a];
    int2 aA3 = adj[(jA3 < s1a) ? jA3 : s0a];
    int jB0 = s0b + p, jB1 = s0b + 8 + p, jB2 = s0b + 16 + p, jB3 = s0b + 24 + p;
    int2 aB0 = adj[(jB0 < s1b) ? jB0 : s0b];
    int2 aB1 = adj[(jB1 < s1b) ? jB1 : s0b];
    int2 aB2 = adj[(jB2 < s1b) ? jB2 : s0b];
    int2 aB3 = adj[(jB3 < s1b) ? jB3 : s0b];

    // ---- gather prologue for BOTH nodes (16 x uint4x2 in flight) ----
    const char* qA0 = xlb + (size_t)(uint)aA0.x + (cl << 5);
    const char* qA1 = xlb + (size_t)(uint)aA1.x + (cl << 5);
    const char* qA2 = xlb + (size_t)(uint)aA2.x + (cl << 5);
    const char* qA3 = xlb + (size_t)(uint)aA3.x + (cl << 5);
    uint4 uA00 = *(const uint4*)qA0, uA01 = *(const uint4*)(qA0 + 16);
    uint4 uA10 = *(const uint4*)qA1, uA11 = *(const uint4*)(qA1 + 16);
    uint4 uA20 = *(const uint4*)qA2, uA21 = *(const uint4*)(qA2 + 16);
    uint4 uA30 = *(const uint4*)qA3, uA31 = *(const uint4*)(qA3 + 16);
    const char* qB0 = xlb + (size_t)(uint)aB0.x + (cl << 5);
    const char* qB1 = xlb + (size_t)(uint)aB1.x + (cl << 5);
    const char* qB2 = xlb + (size_t)(uint)aB2.x + (cl << 5);
    const char* qB3 = xlb + (size_t)(uint)aB3.x + (cl << 5);
    uint4 uB00 = *(const uint4*)qB0, uB01 = *(const uint4*)(qB0 + 16);
    uint4 uB10 = *(const uint4*)qB1, uB11 = *(const uint4*)(qB1 + 16);
    uint4 uB20 = *(const uint4*)qB2, uB21 = *(const uint4*)(qB2 + 16);
    uint4 uB30 = *(const uint4*)qB3, uB31 = *(const uint4*)(qB3 + 16);

    // unpack xr rows
    f32x2 xrlA[8], xrlB[8];
    xrlA[0] = bf2f2(xra0.x); xrlA[1] = bf2f2(xra0.y); xrlA[2] = bf2f2(xra0.z); xrlA[3] = bf2f2(xra0.w);
    xrlA[4] = bf2f2(xra1.x); xrlA[5] = bf2f2(xra1.y); xrlA[6] = bf2f2(xra1.z); xrlA[7] = bf2f2(xra1.w);
    xrlB[0] = bf2f2(xrb0.x); xrlB[1] = bf2f2(xrb0.y); xrlB[2] = bf2f2(xrb0.z); xrlB[3] = bf2f2(xrb0.w);
    xrlB[4] = bf2f2(xrb1.x); xrlB[5] = bf2f2(xrb1.y); xrlB[6] = bf2f2(xrb1.z); xrlB[7] = bf2f2(xrb1.w);

    // consume one 8-edge group held in registers (math identical to verified baseline)
    auto consume = [&](uint4 u0, uint4 u1, float ea_c, bool valid,
                       const f32x2* xrl, float& lr, f32x2* ac) {
        f32x2 xf[8];
        xf[0] = bf2f2(u0.x); xf[1] = bf2f2(u0.y); xf[2] = bf2f2(u0.z); xf[3] = bf2f2(u0.w);
        xf[4] = bf2f2(u1.x); xf[5] = bf2f2(u1.y); xf[6] = bf2f2(u1.z); xf[7] = bf2f2(u1.w);
        f32x2 ea2 = (f32x2){ea_c, ea_c};
        f32x2 s2 = (f32x2){0.f, 0.f};
        #pragma unroll
        for (int k = 0; k < 8; k++) {
            f32x2 m = xf[k] + __builtin_elementwise_fma(ea2, we2[k], xrl[k]);
            m = __builtin_elementwise_max(m, 0.2f * m);     // leaky_relu(0.2)
            s2 = __builtin_elementwise_fma(m, at2[k], s2);
        }
        float s = s2.x + s2.y;
        s += __shfl_xor(s, 1);
        if (H == 1) { s += __shfl_xor(s, 2); s += __shfl_xor(s, 4); }
        if (!valid) s = -1e30f;
        float e = __expf(s);
        lr += e;
        f32x2 e2 = (f32x2){e, e};
        #pragma unroll
        for (int k = 0; k < 8; k++) ac[k] = __builtin_elementwise_fma(e2, xf[k], ac[k]);
    };

    // ---- consume node A ----
    int itersA = (s1a - s0a + 7) >> 3;
    float lA = 0.f;
    f32x2 accA[8];
    #pragma unroll
    for (int k = 0; k < 8; k++) accA[k] = (f32x2){0.f, 0.f};
    consume(uA00, uA01, (jA0 < s1a) ? __int_as_float(aA0.y) : 0.f, jA0 < s1a, xrlA, lA, accA);
    if (itersA > 1) consume(uA10, uA11, (jA1 < s1a) ? __int_as_float(aA1.y) : 0.f, jA1 < s1a, xrlA, lA, accA);
    if (itersA > 2) consume(uA20, uA21, (jA2 < s1a) ? __int_as_float(aA2.y) : 0.f, jA2 < s1a, xrlA, lA, accA);
    if (itersA > 3) consume(uA30, uA31, (jA3 < s1a) ? __int_as_float(aA3.y) : 0.f, jA3 < s1a, xrlA, lA, accA);
    for (int it = 4; it < itersA; ++it) {            // rare tail: degree > 32
        int jn = s0a + it * 8 + p;
        int jb = (jn < s1a) ? jn : s0a;
        int2 pk = adj[jb];
        const char* rp = xlb + (size_t)(uint)pk.x + (cl << 5);
        uint4 nu0 = *(const uint4*)rp;
        uint4 nu1 = *(const uint4*)(rp + 16);
        consume(nu0, nu1, (jn < s1a) ? __int_as_float(pk.y) : 0.f, jn < s1a, xrlA, lA, accA);
    }

    // ---- consume node B ----
    int itersB = (s1b - s0b + 7) >> 3;
    float lB = 0.f;
    f32x2 accB[8];
    #pragma unroll
    for (int k = 0; k < 8; k++) accB[k] = (f32x2){0.f, 0.f};
    consume(uB00, uB01, (jB0 < s1b) ? __int_as_float(aB0.y) : 0.f, jB0 < s1b, xrlB, lB, accB);
    if (itersB > 1) consume(uB10, uB11, (jB1 < s1b) ? __int_as_float(aB1.y) : 0.f, jB1 < s1b, xrlB, lB, accB);
    if (itersB > 2) consume(uB20, uB21, (jB2 < s1b) ? __int_as_float(aB2.y) : 0.f, jB2 < s1b, xrlB, lB, accB);
    if (itersB > 3) consume(uB30, uB31, (jB3 < s1b) ? __int_as_float(aB3.y) : 0.f, jB3 < s1b, xrlB, lB, accB);
    for (int it = 4; it < itersB; ++it) {            // rare tail: degree > 32
        int jn = s0b + it * 8 + p;
        int jb = (jn < s1b) ? jn : s0b;
        int2 pk = adj[jb];
        const char* rp = xlb + (size_t)(uint)pk.x + (cl << 5);
        uint4 nu0 = *(const uint4*)rp;
        uint4 nu1 = *(const uint4*)(rp + 16);
        consume(nu0, nu1, (jn < s1b) ? __int_as_float(pk.y) : 0.f, jn < s1b, xrlB, lB, accB);
    }

    // ---- per-node epilogue (uniform barriers: called exactly twice by all threads) ----
    auto epilogue = [&](int n, float l_run, f32x2* acc) {
        l_run += __shfl_xor(l_run, 8);
        l_run += __shfl_xor(l_run, 16);
        l_run += __shfl_xor(l_run, 32);
        float inv = 1.0f / (l_run + 1e-16f);

        float* row = &accbuf[wv][p][cl * 20];
        #pragma unroll
        for (int i = 0; i < 4; i++)
            *(float4*)&row[4 * i] = make_float4(acc[2 * i].x * inv, acc[2 * i].y * inv,
                                                acc[2 * i + 1].x * inv, acc[2 * i + 1].y * inv);
        __syncthreads();

        float o0 = 0.f, o1 = 0.f;
        #pragma unroll
        for (int q = 0; q < 8; q++) {
            float2 v = *(float2*)&accbuf[wv][q][rb];
            o0 += v.x; o1 += v.y;
        }
        o0 += bias[c0];
        o1 += bias[c0 + 1];

        float sred = o0 + o1;
        #pragma unroll
        for (int off = 1; off < 64; off <<= 1) sred += __shfl_xor(sred, off);
        float mu = sred * (1.f / 128.f);
        float d0 = o0 - mu, d1 = o1 - mu;
        float v = d0 * d0 + d1 * d1;
        #pragma unroll
        for (int off = 1; off < 64; off <<= 1) v += __shfl_xor(v, off);
        float rstd = rsqrtf(v * (1.f / 128.f) + 1e-5f);
        o0 = d0 * rstd * ln_g[c0] + ln_b[c0];
        o1 = d1 * rstd * ln_g[c0 + 1] + ln_b[c0 + 1];

        float2 hv = *(const float2*)&hin[(size_t)n * 128 + c0];
        if (FINAL) {
            float r0 = hv.x + o0, r1 = hv.y + o1;
            int g = n >> 9, rr = n & 511;
            if (rr < 511)
                *(float2*)&outp[((size_t)(g * 511 + rr)) * 128 + c0] = make_float2(r0, r1);
        } else {
            // tanh-approx GELU: x * sigmoid(2u), u = 0.79788456*(x + 0.044715 x^3)
            float t0 = o0 * (0.79788456f + 0.03567741f * o0 * o0);
            o0 = __fdividef(o0, 1.f + __expf(-2.f * t0));
            float t1 = o1 * (0.79788456f + 0.03567741f * o1 * o1);
            o1 = __fdividef(o1, 1.f + __expf(-2.f * t1));
            hv.x += o0; hv.y += o1;
            *(float2*)&hout[(size_t)n * 128 + c0] = hv;
            uint pk = (uint)f2b(hv.x) | ((uint)f2b(hv.y) << 16);
            *(uint*)&hb[(size_t)n * 128 + c0] = pk;
        }
        __syncthreads();   // accbuf reuse guard before next node's writes
    };

    epilogue(nA, lA, accA);
    epilogue(nB, lB, accB);
}

extern "C" void kernel_launch(void* const* d_in, const int* in_sizes, int n_in,
                              void* d_out, int out_size, void* d_ws, size_t ws_size,
                              hipStream_t stream) {
    const float* x        = (const float*)d_in[0];
    const int*   edge_src = (const int*)d_in[1];
    const int*   edge_dst = (const int*)d_in[2];
    const float* edge_attr= (const float*)d_in[3];
    const float* Wl       = (const float*)d_in[4];
    const float* bl       = (const float*)d_in[5];
    const float* Wr       = (const float*)d_in[6];
    const float* br       = (const float*)d_in[7];
    const float* We       = (const float*)d_in[8];
    const float* att      = (const float*)d_in[9];
    const float* bias_p   = (const float*)d_in[10];
    const float* ln_g     = (const float*)d_in[11];
    const float* ln_b     = (const float*)d_in[12];
    float* out = (float*)d_out;

    char* ws = (char*)d_ws;
    float*  h       = (float*)(ws + 0);                 // 33,554,432
    ushort* hb      = (ushort*)(ws + 33554432);         // 16,777,216
    ushort* xl      = (ushort*)(ws + 50331648);         // 16,777,216
    ushort* xr      = (ushort*)(ws + 67108864);         // 16,777,216
    int2*   adj     = (int2*)(ws + 83886080);           //  8,912,896
    int*    row_off = (int*)(ws + 92798976);            //    262,400 (incl pad)
    int*    cnt     = (int*)(ws + 93061376);            //    262,144 (also cursor)
    int*    bsum    = (int*)(ws + 93323520);            //      1,024
    float*  sumbuf  = (float*)(ws + 93324544);          //        256
    ushort* WT      = (ushort*)(ws + 93324800);         //    196,608 (3 layers x 2)

    // 1: transpose weights + zero cnt/sumbuf  (canary out[0]=100)
    k_init<<<dim3(128, 2, 3), 128, 0, stream>>>(Wl, Wr, WT, cnt, sumbuf, out);
    // 2: histogram + edge_attr sum, 4 edges/thread  (canary out[1]=120)
    k_histsum<<<TOTE / 1024, 256, 0, stream>>>(edge_dst, edge_attr, cnt, sumbuf, out);
    // 3-4: scan                               (canaries out[2]=140, out[3]=160)
    k_scanA<<<NN / 256, 256, 0, stream>>>(cnt, row_off, bsum, out);
    k_scanC<<<NN / 256, 256, 0, stream>>>(row_off, bsum, cnt, out);
    // 5: scatter, 4 edges/thread (adj.x = src byte offset)  (canary out[4]=180)
    k_scatter<<<TOTE / 1024, 256, 0, stream>>>(edge_src, edge_dst, edge_attr, sumbuf, cnt, adj, out);

    // layer 0: GEMM from fp32 x; residual from x   (canaries out[5]=200, out[6]=220)
    k_gemm<true><<<NN / 128, 512, 0, stream>>>(x, WT, bl, br, xl, xr, out, 5, 200.0f);
    k_attn<4, false><<<NN / 4, 128, 0, stream>>>(xl, xr, row_off, adj,
                                                 We, att, bias_p, ln_g, ln_b,
                                                 x, h, hb, nullptr, out, 6, 220.0f);
    // layer 1                                       (canaries out[7]=240, out[8]=260)
    k_gemm<false><<<NN / 128, 512, 0, stream>>>(hb, WT + 32768, bl + 128, br + 128, xl, xr, out, 7, 240.0f);
    k_attn<4, false><<<NN / 4, 128, 0, stream>>>(xl, xr, row_off, adj,
                                                 We + 128, att + 128, bias_p + 128,
                                                 ln_g + 128, ln_b + 128,
                                                 h, h, hb, nullptr, out, 8, 260.0f);
    // layer 2 (final): writes out directly, drops virtual node
    // (canary out[9]=280 from the gemm; final attn overwrites out[0..9] with real values)
    k_gemm<false><<<NN / 128, 512, 0, stream>>>(hb, WT + 65536, bl + 256, br + 256, xl, xr, out, 9, 280.0f);
    k_attn<1, true><<<NN / 4, 128, 0, stream>>>(xl, xr, row_off, adj,
                                                We + 256, att + 256, bias_p + 256,
                                                ln_g + 256, ln_b + 256,
                                                h, nullptr, nullptr, out, nullptr, 0, 0.0f);
}